// Round 3
// baseline (1148.703 us; speedup 1.0000x reference)
//
#include <hip/hip_runtime.h>
#include <cstdint>
#include <cstddef>

// RWKV block on MI355X (gfx950).
//   convert weights fp32->bf16 (7 matrices)
//   ln_mix<3>: LN1 + token-shift lerp -> xk,xv,xr (bf16)
//   gemm k, v (bf16 out), sigmoid-r (bf16 out)   [m97 128^2 MFMA structure]
//   wkv 3-phase chunked scan (128 chunks x 64 tokens), phase3 fuses *sigmoid(r) -> bf16
//   gemm rz = x + wkv@atto^T + b (f32)
//   ln_mix<2>: LN2 + shift lerp -> xkf,xrf (bf16)
//   gemm rf = sigmoid (bf16), gemm kf2 = relu^2 (bf16), gemm out = kf2@ffnv^T*rf + rz (f32)

#define SEQ 8192
#define DIM 2048
#define NCH 128   // chunks for wkv scan
#define CL  64    // tokens per chunk (SEQ/NCH)

typedef unsigned short u16;
typedef __attribute__((ext_vector_type(8))) short bf16x8;
typedef __attribute__((ext_vector_type(4))) float f32x4;

__device__ __forceinline__ u16 f2bf(float f) {
  unsigned x = __float_as_uint(f);
  x += 0x7fffu + ((x >> 16) & 1u);   // round-to-nearest-even
  return (u16)(x >> 16);
}
__device__ __forceinline__ float bf2f(u16 h) {
  return __uint_as_float((unsigned)h << 16);
}

// ---------------- weight conversion fp32 -> bf16 ----------------
__global__ void __launch_bounds__(256) convert_weights(
    const float* w0, const float* w1, const float* w2, const float* w3,
    const float* w4, const float* w5, const float* w6, u16* dst)
{
  const float* s;
  switch (blockIdx.y) {
    case 0: s = w0; break; case 1: s = w1; break; case 2: s = w2; break;
    case 3: s = w3; break; case 4: s = w4; break; case 5: s = w5; break;
    default: s = w6; break;
  }
  size_t i = ((size_t)blockIdx.x * 256 + threadIdx.x) * 4;
  float4 f = *(const float4*)(s + i);
  *(ushort4*)(dst + (size_t)blockIdx.y * DIM * DIM + i) =
      make_ushort4(f2bf(f.x), f2bf(f.y), f2bf(f.z), f2bf(f.w));
}

// ---------------- fused LayerNorm + token-shift lerp -> bf16 ----------------
__device__ __forceinline__ void store_mix8(u16* dst, const float* mix,
                                           const float* yc, const float* yp)
{
  float4 ma = *(const float4*)(mix);
  float4 mb = *(const float4*)(mix + 4);
  float mv[8] = {ma.x, ma.y, ma.z, ma.w, mb.x, mb.y, mb.z, mb.w};
  u16 uu[8];
  #pragma unroll
  for (int j = 0; j < 8; ++j)
    uu[j] = f2bf(yp[j] + mv[j] * (yc[j] - yp[j]));   // lerp(prev, cur, mix)
  *(ushort4*)dst       = make_ushort4(uu[0], uu[1], uu[2], uu[3]);
  *(ushort4*)(dst + 4) = make_ushort4(uu[4], uu[5], uu[6], uu[7]);
}

template<int NOUT>
__global__ void __launch_bounds__(256) ln_mix_kernel(
    const float* __restrict__ X, const float* __restrict__ gw, const float* __restrict__ bw,
    const float* __restrict__ mix0, const float* __restrict__ mix1, const float* __restrict__ mix2,
    u16* __restrict__ o0, u16* __restrict__ o1, u16* __restrict__ o2)
{
  const int t  = blockIdx.x;
  const int tp = (t == 0) ? (SEQ - 1) : (t - 1);   // jnp.roll(,1): tc[t] = xy[t-1], wraps
  const int tid = threadIdx.x, lane = tid & 63, wid = tid >> 6;
  const int base = tid * 8;
  const float* xc = X + (size_t)t  * DIM + base;
  const float* xp = X + (size_t)tp * DIM + base;
  float4 ca = *(const float4*)xc, cb2 = *(const float4*)(xc + 4);
  float4 pa = *(const float4*)xp, pb2 = *(const float4*)(xp + 4);
  float cv[8] = {ca.x, ca.y, ca.z, ca.w, cb2.x, cb2.y, cb2.z, cb2.w};
  float pv[8] = {pa.x, pa.y, pa.z, pa.w, pb2.x, pb2.y, pb2.z, pb2.w};
  float4 s = {0.f, 0.f, 0.f, 0.f};
  #pragma unroll
  for (int j = 0; j < 8; ++j) {
    s.x += cv[j]; s.y += cv[j] * cv[j];
    s.z += pv[j]; s.w += pv[j] * pv[j];
  }
  #pragma unroll
  for (int off = 32; off > 0; off >>= 1) {
    s.x += __shfl_down(s.x, off);
    s.y += __shfl_down(s.y, off);
    s.z += __shfl_down(s.z, off);
    s.w += __shfl_down(s.w, off);
  }
  __shared__ float4 wred[4];
  if (lane == 0) wred[wid] = s;
  __syncthreads();
  float4 tt;
  tt.x = wred[0].x + wred[1].x + wred[2].x + wred[3].x;
  tt.y = wred[0].y + wred[1].y + wred[2].y + wred[3].y;
  tt.z = wred[0].z + wred[1].z + wred[2].z + wred[3].z;
  tt.w = wred[0].w + wred[1].w + wred[2].w + wred[3].w;
  constexpr float inv = 1.0f / DIM;
  const float mc = tt.x * inv, vc = tt.y * inv - mc * mc;
  const float rc = 1.0f / sqrtf(vc + 1e-5f);
  const float mp = tt.z * inv, vp = tt.w * inv - mp * mp;
  const float rp = 1.0f / sqrtf(vp + 1e-5f);
  float4 ga = *(const float4*)(gw + base), gb = *(const float4*)(gw + base + 4);
  float4 ba = *(const float4*)(bw + base), bb = *(const float4*)(bw + base + 4);
  float gv[8] = {ga.x, ga.y, ga.z, ga.w, gb.x, gb.y, gb.z, gb.w};
  float bv[8] = {ba.x, ba.y, ba.z, ba.w, bb.x, bb.y, bb.z, bb.w};
  float yc[8], yp[8];
  #pragma unroll
  for (int j = 0; j < 8; ++j) {
    yc[j] = (cv[j] - mc) * rc * gv[j] + bv[j];
    yp[j] = (pv[j] - mp) * rp * gv[j] + bv[j];
  }
  store_mix8(o0 + (size_t)t * DIM + base, mix0 + base, yc, yp);
  store_mix8(o1 + (size_t)t * DIM + base, mix1 + base, yc, yp);
  if constexpr (NOUT == 3)
    store_mix8(o2 + (size_t)t * DIM + base, mix2 + base, yc, yp);
}

// ---------------- bf16 MFMA GEMM: C[M,N] = A[M,K] @ B[N,K]^T  (m97 structure) ----------------
// EPI: 0 = +bias            -> bf16
//      1 = sigmoid(+bias)   -> bf16
//      2 = +bias + exf      -> f32   (residual add)
//      3 = relu(+bias)^2    -> bf16
//      4 = (+bias)*exb + exf-> f32   (final: rvm*rf + rz)
template<int EPI>
__global__ void __launch_bounds__(256) gemm_bt(
    const u16* __restrict__ A, const u16* __restrict__ B,
    const float* __restrict__ bias,
    const float* __restrict__ exf, const u16* __restrict__ exb,
    float* __restrict__ Cf, u16* __restrict__ Cb)
{
  constexpr int BK = 32;
  __shared__ u16 As[128 * BK];
  __shared__ u16 Bs[128 * BK];
  const int tid  = threadIdx.x;
  const int lane = tid & 63;
  const int wid  = tid >> 6;
  const int wr = wid >> 1, wc = wid & 1;          // 2x2 waves, 64x64 each
  const int tm = blockIdx.y * 128, tn = blockIdx.x * 128;
  const int frow = lane & 15, fko = (lane >> 4) * 8;
  const int cb = wid * 2;                          // staging chunk-group base
  f32x4 acc[4][4] = {};

  for (int k0 = 0; k0 < DIM; k0 += BK) {
    __syncthreads();   // previous iteration's ds_reads done before overwrite
    #pragma unroll
    for (int j = 0; j < 2; ++j) {
      const int chunk = (cb + j) * 64 + lane;      // 512 chunks of 16B = 8KB tile
      const int row = chunk >> 2;
      const int c8  = (chunk & 3) * 8;
      const u16* ga = A + (size_t)(tm + row) * DIM + k0 + c8;
      const u16* gb = B + (size_t)(tn + row) * DIM + k0 + c8;
      __builtin_amdgcn_global_load_lds(
          (const __attribute__((address_space(1))) void*)ga,
          (__attribute__((address_space(3))) void*)(As + (cb + j) * 512), 16, 0, 0);
      __builtin_amdgcn_global_load_lds(
          (const __attribute__((address_space(1))) void*)gb,
          (__attribute__((address_space(3))) void*)(Bs + (cb + j) * 512), 16, 0, 0);
    }
    __syncthreads();   // drains vmcnt: LDS tiles ready
    bf16x8 af[4], bf[4];
    #pragma unroll
    for (int m = 0; m < 4; ++m)
      af[m] = *(const bf16x8*)(As + (wr * 64 + m * 16 + frow) * BK + fko);
    #pragma unroll
    for (int n = 0; n < 4; ++n)
      bf[n] = *(const bf16x8*)(Bs + (wc * 64 + n * 16 + frow) * BK + fko);
    #pragma unroll
    for (int m = 0; m < 4; ++m)
      #pragma unroll
      for (int n = 0; n < 4; ++n)
        acc[m][n] = __builtin_amdgcn_mfma_f32_16x16x32_bf16(af[m], bf[n], acc[m][n], 0, 0, 0);
  }

  // epilogue; C/D layout: col = lane&15, row = (lane>>4)*4 + i  [m89-verified]
  #pragma unroll
  for (int n = 0; n < 4; ++n) {
    const int cn = tn + wc * 64 + n * 16 + frow;
    const float bv = bias[cn];
    #pragma unroll
    for (int m = 0; m < 4; ++m) {
      const int r0 = tm + wr * 64 + m * 16 + (lane >> 4) * 4;
      #pragma unroll
      for (int i = 0; i < 4; ++i) {
        const size_t idx = (size_t)(r0 + i) * DIM + cn;
        float val = acc[m][n][i] + bv;
        if constexpr (EPI == 0)      { Cb[idx] = f2bf(val); }
        else if constexpr (EPI == 1) { Cb[idx] = f2bf(1.0f / (1.0f + __expf(-val))); }
        else if constexpr (EPI == 2) { Cf[idx] = val + exf[idx]; }
        else if constexpr (EPI == 3) { float r = fmaxf(val, 0.0f); Cb[idx] = f2bf(r * r); }
        else                         { Cf[idx] = val * bf2f(exb[idx]) + exf[idx]; }
      }
    }
  }
}

// ---------------- WKV chunked scan ----------------
// State (aa,bb,pp) represents numerator aa*e^pp, denominator bb*e^pp.
// One step (unnormalized space): A' = e^w * A + e^k * v  -- linear.
// Phase 1: per-chunk local state from zero init.
__global__ void __launch_bounds__(256) wkv_phase1(
    const u16* __restrict__ k, const u16* __restrict__ v,
    const float* __restrict__ tdec,
    float* __restrict__ Sa, float* __restrict__ Sb, float* __restrict__ Sp)
{
  const int d = blockIdx.y * 256 + threadIdx.x;
  const int c = blockIdx.x;
  const float w = -__expf(tdec[d]);
  float aa = 0.f, bb = 0.f, pp = -1e38f;
  const int t0 = c * CL;
  for (int t = t0; t < t0 + CL; ++t) {
    const size_t idx = (size_t)t * DIM + d;
    const float kk = bf2f(k[idx]), vv = bf2f(v[idx]);
    const float ww2 = pp + w;
    const float p2 = fmaxf(ww2, kk);
    const float e1 = __expf(ww2 - p2), e2 = __expf(kk - p2);
    aa = e1 * aa + e2 * vv;
    bb = e1 * bb + e2;
    pp = p2;
  }
  Sa[(size_t)c * DIM + d] = aa;
  Sb[(size_t)c * DIM + d] = bb;
  Sp[(size_t)c * DIM + d] = pp;
}

// Phase 2: sequential fold; P_c = prefix state BEFORE chunk c.
// state_after(c) = Decay_CL(state_before) (+) S_c ; Decay_CL: pp += CL*w.
__global__ void __launch_bounds__(256) wkv_phase2(
    const float* __restrict__ Sa, const float* __restrict__ Sb, const float* __restrict__ Sp,
    const float* __restrict__ tdec,
    float* __restrict__ Pa, float* __restrict__ Pb, float* __restrict__ Pp)
{
  const int d = blockIdx.x * 256 + threadIdx.x;
  const float w = -__expf(tdec[d]);
  const float Lw = (float)CL * w;
  float aa = 0.f, bb = 0.f, pp = -1e38f;
  for (int c = 0; c < NCH; ++c) {
    const size_t idx = (size_t)c * DIM + d;
    Pa[idx] = aa; Pb[idx] = bb; Pp[idx] = pp;
    const float dp = pp + Lw;
    const float sa = Sa[idx], sb = Sb[idx], sp = Sp[idx];
    const float p = fmaxf(dp, sp);
    const float e1 = __expf(dp - p), e2 = __expf(sp - p);
    aa = e1 * aa + e2 * sa;
    bb = e1 * bb + e2 * sb;
    pp = p;
  }
}

// Phase 3: replay chunk from prefix state, emit out*sigmoid_r as bf16.
__global__ void __launch_bounds__(256) wkv_phase3(
    const u16* __restrict__ k, const u16* __restrict__ v, const u16* __restrict__ r,
    const float* __restrict__ Pa, const float* __restrict__ Pb, const float* __restrict__ Pp,
    const float* __restrict__ tfirst, const float* __restrict__ tdec,
    u16* __restrict__ outb)
{
  const int d = blockIdx.y * 256 + threadIdx.x;
  const int c = blockIdx.x;
  const float u = tfirst[d];
  const float w = -__expf(tdec[d]);
  const size_t sidx = (size_t)c * DIM + d;
  float aa = Pa[sidx], bb = Pb[sidx], pp = Pp[sidx];
  const int t0 = c * CL;
  for (int t = t0; t < t0 + CL; ++t) {
    const size_t idx = (size_t)t * DIM + d;
    const float kk = bf2f(k[idx]), vv = bf2f(v[idx]);
    // output uses carry (tokens < t) plus u-bonus for current token
    const float ww = u + kk;
    const float p = fmaxf(pp, ww);
    float e1 = __expf(pp - p), e2 = __expf(ww - p);
    const float out = (e1 * aa + e2 * vv) / (e1 * bb + e2);
    outb[idx] = f2bf(out * bf2f(r[idx]));
    // state update
    const float ww2 = pp + w;
    const float p2 = fmaxf(ww2, kk);
    e1 = __expf(ww2 - p2); e2 = __expf(kk - p2);
    aa = e1 * aa + e2 * vv;
    bb = e1 * bb + e2;
    pp = p2;
  }
}

// ---------------- host-side orchestration ----------------
extern "C" void kernel_launch(void* const* d_in, const int* in_sizes, int n_in,
                              void* d_out, int out_size, void* d_ws, size_t ws_size,
                              hipStream_t stream)
{
  const float* x      = (const float*)d_in[0];
  const float* attk_w = (const float*)d_in[1];
  const float* attk_b = (const float*)d_in[2];
  const float* attv_w = (const float*)d_in[3];
  const float* attv_b = (const float*)d_in[4];
  const float* attr_w = (const float*)d_in[5];
  const float* attr_b = (const float*)d_in[6];
  const float* atto_w = (const float*)d_in[7];
  const float* atto_b = (const float*)d_in[8];
  const float* ffnk_w = (const float*)d_in[9];
  const float* ffnk_b = (const float*)d_in[10];
  const float* ffnv_w = (const float*)d_in[11];
  const float* ffnv_b = (const float*)d_in[12];
  const float* ffnr_w = (const float*)d_in[13];
  const float* ffnr_b = (const float*)d_in[14];
  const float* ln1_g  = (const float*)d_in[15];
  const float* ln1_b  = (const float*)d_in[16];
  const float* ln2_g  = (const float*)d_in[17];
  const float* ln2_b  = (const float*)d_in[18];
  const float* amixk  = (const float*)d_in[19];
  const float* amixv  = (const float*)d_in[20];
  const float* amixr  = (const float*)d_in[21];
  const float* fmixk  = (const float*)d_in[22];
  const float* fmixr  = (const float*)d_in[23];
  const float* tfirst = (const float*)d_in[24];
  const float* tdecay = (const float*)d_in[25];
  float* out = (float*)d_out;

  // workspace carve-up: peak ~254 MiB with aliasing.
  const size_t WE = (size_t)DIM * DIM;   // weight elements
  const size_t SD = (size_t)SEQ * DIM;   // activation elements
  u16* Wbf = (u16*)d_ws;                 // 7 * 8 MiB bf16 weights
  u16* xk  = Wbf + 7 * WE;               // 32 MiB  (later wkvr, later kf2)
  u16* xv  = xk + SD;                    // 32 MiB  (later rz lower half)
  u16* xr  = xv + SD;                    // 32 MiB  (rz upper half)
  u16* kb  = xr + SD;                    // bf16 k  (later xkf)
  u16* vb  = kb + SD;                    // bf16 v  (later xrf)
  u16* rb  = vb + SD;                    // bf16 r  (later rf)
  float* Sa = (float*)(rb + SD);         // 6 x 1 MiB scan states
  float* Sb = Sa + (size_t)NCH * DIM;
  float* Sp = Sb + (size_t)NCH * DIM;
  float* Pa = Sp + (size_t)NCH * DIM;
  float* Pb = Pa + (size_t)NCH * DIM;
  float* Pp = Pb + (size_t)NCH * DIM;
  // aliases (lifetimes disjoint):
  u16*   wkvr = xk;          // wkv*r output, consumed by rz gemm
  float* rz   = (float*)xv;  // f32, spans xv+xr (64 MiB)
  u16*   xkf  = kb;
  u16*   xrf  = vb;
  u16*   rf   = rb;
  u16*   kf2  = xk;

  const dim3 gg(DIM / 128, SEQ / 128);
  const dim3 gwkv(NCH, DIM / 256);

  convert_weights<<<dim3(DIM * DIM / 1024, 7), 256, 0, stream>>>(
      attk_w, attv_w, attr_w, atto_w, ffnk_w, ffnv_w, ffnr_w, Wbf);

  // --- attention branch ---
  ln_mix_kernel<3><<<SEQ, 256, 0, stream>>>(x, ln1_g, ln1_b, amixk, amixv, amixr, xk, xv, xr);
  gemm_bt<0><<<gg, 256, 0, stream>>>(xk, Wbf + 0 * WE, attk_b, nullptr, nullptr, nullptr, kb);
  gemm_bt<0><<<gg, 256, 0, stream>>>(xv, Wbf + 1 * WE, attv_b, nullptr, nullptr, nullptr, vb);
  gemm_bt<1><<<gg, 256, 0, stream>>>(xr, Wbf + 2 * WE, attr_b, nullptr, nullptr, nullptr, rb);
  wkv_phase1<<<gwkv, 256, 0, stream>>>(kb, vb, tdecay, Sa, Sb, Sp);
  wkv_phase2<<<DIM / 256, 256, 0, stream>>>(Sa, Sb, Sp, tdecay, Pa, Pb, Pp);
  wkv_phase3<<<gwkv, 256, 0, stream>>>(kb, vb, rb, Pa, Pb, Pp, tfirst, tdecay, wkvr);
  // rz = x + wkv@atto^T + b   (wkvr in xk; rz into xv+xr region)
  gemm_bt<2><<<gg, 256, 0, stream>>>(wkvr, Wbf + 3 * WE, atto_b, x, nullptr, rz, nullptr);

  // --- channel-mix branch ---
  ln_mix_kernel<2><<<SEQ, 256, 0, stream>>>(rz, ln2_g, ln2_b, fmixk, fmixr, nullptr, xkf, xrf, nullptr);
  gemm_bt<1><<<gg, 256, 0, stream>>>(xrf, Wbf + 6 * WE, ffnr_b, nullptr, nullptr, nullptr, rf);  // rf
  gemm_bt<3><<<gg, 256, 0, stream>>>(xkf, Wbf + 4 * WE, ffnk_b, nullptr, nullptr, nullptr, kf2); // kf^2
  gemm_bt<4><<<gg, 256, 0, stream>>>(kf2, Wbf + 5 * WE, ffnv_b, rz, rf, out, nullptr);           // final
}

// Round 8
// 1005.528 us; speedup vs baseline: 1.1424x; 1.1424x over previous
//
#include <hip/hip_runtime.h>
#include <cstdint>
#include <cstddef>

// RWKV block on MI355X (gfx950).
//   convert weights fp32->bf16 (7 matrices)
//   ln_mix<3>: LN1 + token-shift lerp -> xk,xv,xr (bf16)
//   gemm k, v (bf16 out), sigmoid-r (bf16 out)   [2-phase dbuf 128^2 MFMA structure]
//   wkv 3-phase chunked scan (128 chunks x 64 tokens), phase3 fuses *sigmoid(r) -> bf16
//   gemm rz = x + wkv@atto^T + b (f32)
//   ln_mix<2>: LN2 + shift lerp -> xkf,xrf (bf16)
//   gemm rf = sigmoid (bf16), gemm kf2 = relu^2 (bf16), gemm out = kf2@ffnv^T*rf + rz (f32)

#define SEQ 8192
#define DIM 2048
#define NCH 128   // chunks for wkv scan
#define CL  64    // tokens per chunk (SEQ/NCH)

typedef unsigned short u16;
typedef __attribute__((ext_vector_type(8))) short bf16x8;
typedef __attribute__((ext_vector_type(4))) float f32x4;

__device__ __forceinline__ u16 f2bf(float f) {
  unsigned x = __float_as_uint(f);
  x += 0x7fffu + ((x >> 16) & 1u);   // round-to-nearest-even
  return (u16)(x >> 16);
}
__device__ __forceinline__ float bf2f(u16 h) {
  return __uint_as_float((unsigned)h << 16);
}

// ---------------- weight conversion fp32 -> bf16 ----------------
__global__ void __launch_bounds__(256) convert_weights(
    const float* w0, const float* w1, const float* w2, const float* w3,
    const float* w4, const float* w5, const float* w6, u16* dst)
{
  const float* s;
  switch (blockIdx.y) {
    case 0: s = w0; break; case 1: s = w1; break; case 2: s = w2; break;
    case 3: s = w3; break; case 4: s = w4; break; case 5: s = w5; break;
    default: s = w6; break;
  }
  size_t i = ((size_t)blockIdx.x * 256 + threadIdx.x) * 4;
  float4 f = *(const float4*)(s + i);
  *(ushort4*)(dst + (size_t)blockIdx.y * DIM * DIM + i) =
      make_ushort4(f2bf(f.x), f2bf(f.y), f2bf(f.z), f2bf(f.w));
}

// ---------------- fused LayerNorm + token-shift lerp -> bf16 ----------------
__device__ __forceinline__ void store_mix8(u16* dst, const float* mix,
                                           const float* yc, const float* yp)
{
  float4 ma = *(const float4*)(mix);
  float4 mb = *(const float4*)(mix + 4);
  float mv[8] = {ma.x, ma.y, ma.z, ma.w, mb.x, mb.y, mb.z, mb.w};
  u16 uu[8];
  #pragma unroll
  for (int j = 0; j < 8; ++j)
    uu[j] = f2bf(yp[j] + mv[j] * (yc[j] - yp[j]));   // lerp(prev, cur, mix)
  *(ushort4*)dst       = make_ushort4(uu[0], uu[1], uu[2], uu[3]);
  *(ushort4*)(dst + 4) = make_ushort4(uu[4], uu[5], uu[6], uu[7]);
}

template<int NOUT>
__global__ void __launch_bounds__(256) ln_mix_kernel(
    const float* __restrict__ X, const float* __restrict__ gw, const float* __restrict__ bw,
    const float* __restrict__ mix0, const float* __restrict__ mix1, const float* __restrict__ mix2,
    u16* __restrict__ o0, u16* __restrict__ o1, u16* __restrict__ o2)
{
  const int t  = blockIdx.x;
  const int tp = (t == 0) ? (SEQ - 1) : (t - 1);   // jnp.roll(,1): tc[t] = xy[t-1], wraps
  const int tid = threadIdx.x, lane = tid & 63, wid = tid >> 6;
  const int base = tid * 8;
  const float* xc = X + (size_t)t  * DIM + base;
  const float* xp = X + (size_t)tp * DIM + base;
  float4 ca = *(const float4*)xc, cb2 = *(const float4*)(xc + 4);
  float4 pa = *(const float4*)xp, pb2 = *(const float4*)(xp + 4);
  float cv[8] = {ca.x, ca.y, ca.z, ca.w, cb2.x, cb2.y, cb2.z, cb2.w};
  float pv[8] = {pa.x, pa.y, pa.z, pa.w, pb2.x, pb2.y, pb2.z, pb2.w};
  float4 s = {0.f, 0.f, 0.f, 0.f};
  #pragma unroll
  for (int j = 0; j < 8; ++j) {
    s.x += cv[j]; s.y += cv[j] * cv[j];
    s.z += pv[j]; s.w += pv[j] * pv[j];
  }
  #pragma unroll
  for (int off = 32; off > 0; off >>= 1) {
    s.x += __shfl_down(s.x, off);
    s.y += __shfl_down(s.y, off);
    s.z += __shfl_down(s.z, off);
    s.w += __shfl_down(s.w, off);
  }
  __shared__ float4 wred[4];
  if (lane == 0) wred[wid] = s;
  __syncthreads();
  float4 tt;
  tt.x = wred[0].x + wred[1].x + wred[2].x + wred[3].x;
  tt.y = wred[0].y + wred[1].y + wred[2].y + wred[3].y;
  tt.z = wred[0].z + wred[1].z + wred[2].z + wred[3].z;
  tt.w = wred[0].w + wred[1].w + wred[2].w + wred[3].w;
  constexpr float inv = 1.0f / DIM;
  const float mc = tt.x * inv, vc = tt.y * inv - mc * mc;
  const float rc = 1.0f / sqrtf(vc + 1e-5f);
  const float mp = tt.z * inv, vp = tt.w * inv - mp * mp;
  const float rp = 1.0f / sqrtf(vp + 1e-5f);
  float4 ga = *(const float4*)(gw + base), gb = *(const float4*)(gw + base + 4);
  float4 ba = *(const float4*)(bw + base), bb = *(const float4*)(bw + base + 4);
  float gv[8] = {ga.x, ga.y, ga.z, ga.w, gb.x, gb.y, gb.z, gb.w};
  float bv[8] = {ba.x, ba.y, ba.z, ba.w, bb.x, bb.y, bb.z, bb.w};
  float yc[8], yp[8];
  #pragma unroll
  for (int j = 0; j < 8; ++j) {
    yc[j] = (cv[j] - mc) * rc * gv[j] + bv[j];
    yp[j] = (pv[j] - mp) * rp * gv[j] + bv[j];
  }
  store_mix8(o0 + (size_t)t * DIM + base, mix0 + base, yc, yp);
  store_mix8(o1 + (size_t)t * DIM + base, mix1 + base, yc, yp);
  if constexpr (NOUT == 3)
    store_mix8(o2 + (size_t)t * DIM + base, mix2 + base, yc, yp);
}

// ---------------- bf16 MFMA GEMM: C[M,N] = A[M,K] @ B[N,K]^T ----------------
// 2-phase double-buffered LDS (stage t+1 while computing t), XCD-aware swizzle.
// EPI: 0 = +bias            -> bf16
//      1 = sigmoid(+bias)   -> bf16
//      2 = +bias + exf      -> f32   (residual add)
//      3 = relu(+bias)^2    -> bf16
//      4 = (+bias)*exb + exf-> f32   (final: rvm*rf + rz)
template<int EPI>
__global__ void __launch_bounds__(256, 4) gemm_bt(
    const u16* __restrict__ A, const u16* __restrict__ B,
    const float* __restrict__ bias,
    const float* __restrict__ exf, const u16* __restrict__ exb,
    float* __restrict__ Cf, u16* __restrict__ Cb)
{
  constexpr int BK = 32;
  constexpr int NT = DIM / BK;           // 64 K-steps
  __shared__ u16 As[2][128 * BK];        // 2 x 8 KB
  __shared__ u16 Bs[2][128 * BK];
  const int tid  = threadIdx.x;
  const int lane = tid & 63;
  const int wid  = tid >> 6;
  const int wr = wid >> 1, wc = wid & 1;          // 2x2 waves, 64x64 each
  // XCD-aware bijective swizzle: 1024 blocks = 8 XCDs x 128-chunk; blocks in a
  // chunk share A-panels (n fastest), keeping A in the XCD's private L2.
  const int bid = blockIdx.y * gridDim.x + blockIdx.x;    // dispatch order, x fastest
  const int nb  = (bid & 7) * 128 + (bid >> 3);
  const int tn  = (nb & 15) * 128;
  const int tm  = (nb >> 4) * 128;
  const int frow = lane & 15, fko = (lane >> 4) * 8;
  const int cb = wid * 2;                          // staging chunk-group base
  f32x4 acc[4][4] = {};

  // stage K-tile k0 into buffer b: 512 chunks of 16B per matrix (linear row-major)
#define GSTAGE(b, k0)                                                           \
  {                                                                             \
    _Pragma("unroll")                                                           \
    for (int j = 0; j < 2; ++j) {                                               \
      const int chunk = (cb + j) * 64 + lane;                                   \
      const int row = chunk >> 2;                                               \
      const int c8  = (chunk & 3) * 8;                                          \
      const u16* ga = A + (size_t)(tm + row) * DIM + (k0) + c8;                 \
      const u16* gb = B + (size_t)(tn + row) * DIM + (k0) + c8;                 \
      __builtin_amdgcn_global_load_lds(                                         \
          (const __attribute__((address_space(1))) void*)ga,                    \
          (__attribute__((address_space(3))) void*)(&As[b][0] + (cb + j) * 512),\
          16, 0, 0);                                                            \
      __builtin_amdgcn_global_load_lds(                                         \
          (const __attribute__((address_space(1))) void*)gb,                    \
          (__attribute__((address_space(3))) void*)(&Bs[b][0] + (cb + j) * 512),\
          16, 0, 0);                                                            \
    }                                                                           \
  }

#define GCOMPUTE(b)                                                             \
  {                                                                             \
    bf16x8 af[4], bfr[4];                                                       \
    _Pragma("unroll")                                                           \
    for (int m = 0; m < 4; ++m)                                                 \
      af[m] = *(const bf16x8*)(&As[b][0] + (wr * 64 + m * 16 + frow) * BK + fko);\
    _Pragma("unroll")                                                           \
    for (int n = 0; n < 4; ++n)                                                 \
      bfr[n] = *(const bf16x8*)(&Bs[b][0] + (wc * 64 + n * 16 + frow) * BK + fko);\
    _Pragma("unroll")                                                           \
    for (int m = 0; m < 4; ++m)                                                 \
      _Pragma("unroll")                                                         \
      for (int n = 0; n < 4; ++n)                                               \
        acc[m][n] = __builtin_amdgcn_mfma_f32_16x16x32_bf16(af[m], bfr[n],      \
                                                            acc[m][n], 0, 0, 0);\
  }

  GSTAGE(0, 0);
  __syncthreads();                       // implicit vmcnt(0): tile 0 resident
  #pragma unroll 1
  for (int t = 0; t < NT; t += 2) {
    // even step: stage t+1 into buf1 (overlaps), compute buf0
    GSTAGE(1, (t + 1) * BK);             // t+1 <= 63 always
    GCOMPUTE(0);
    __syncthreads();                     // drains vmcnt+lgkm: buf1 ready, buf0 free
    // odd step: stage t+2 into buf0 (unless done), compute buf1
    if (t + 2 < NT) GSTAGE(0, (t + 2) * BK);
    GCOMPUTE(1);
    __syncthreads();
  }
#undef GSTAGE
#undef GCOMPUTE

  // epilogue; C/D layout: col = lane&15, row = (lane>>4)*4 + i  [m89-verified]
  #pragma unroll
  for (int n = 0; n < 4; ++n) {
    const int cn = tn + wc * 64 + n * 16 + frow;
    const float bv = bias[cn];
    #pragma unroll
    for (int m = 0; m < 4; ++m) {
      const int r0 = tm + wr * 64 + m * 16 + (lane >> 4) * 4;
      #pragma unroll
      for (int i = 0; i < 4; ++i) {
        const size_t idx = (size_t)(r0 + i) * DIM + cn;
        float val = acc[m][n][i] + bv;
        if constexpr (EPI == 0)      { Cb[idx] = f2bf(val); }
        else if constexpr (EPI == 1) { Cb[idx] = f2bf(1.0f / (1.0f + __expf(-val))); }
        else if constexpr (EPI == 2) { Cf[idx] = val + exf[idx]; }
        else if constexpr (EPI == 3) { float r = fmaxf(val, 0.0f); Cb[idx] = f2bf(r * r); }
        else                         { Cf[idx] = val * bf2f(exb[idx]) + exf[idx]; }
      }
    }
  }
}

// ---------------- WKV chunked scan ----------------
// State (aa,bb,pp) represents numerator aa*e^pp, denominator bb*e^pp.
// One step (unnormalized space): A' = e^w * A + e^k * v  -- linear.
// Phase 1: per-chunk local state from zero init.
__global__ void __launch_bounds__(256) wkv_phase1(
    const u16* __restrict__ k, const u16* __restrict__ v,
    const float* __restrict__ tdec,
    float* __restrict__ Sa, float* __restrict__ Sb, float* __restrict__ Sp)
{
  const int d = blockIdx.y * 256 + threadIdx.x;
  const int c = blockIdx.x;
  const float w = -__expf(tdec[d]);
  float aa = 0.f, bb = 0.f, pp = -1e38f;
  const int t0 = c * CL;
  for (int t = t0; t < t0 + CL; ++t) {
    const size_t idx = (size_t)t * DIM + d;
    const float kk = bf2f(k[idx]), vv = bf2f(v[idx]);
    const float ww2 = pp + w;
    const float p2 = fmaxf(ww2, kk);
    const float e1 = __expf(ww2 - p2), e2 = __expf(kk - p2);
    aa = e1 * aa + e2 * vv;
    bb = e1 * bb + e2;
    pp = p2;
  }
  Sa[(size_t)c * DIM + d] = aa;
  Sb[(size_t)c * DIM + d] = bb;
  Sp[(size_t)c * DIM + d] = pp;
}

// Phase 2: sequential fold; P_c = prefix state BEFORE chunk c.
// state_after(c) = Decay_CL(state_before) (+) S_c ; Decay_CL: pp += CL*w.
__global__ void __launch_bounds__(256) wkv_phase2(
    const float* __restrict__ Sa, const float* __restrict__ Sb, const float* __restrict__ Sp,
    const float* __restrict__ tdec,
    float* __restrict__ Pa, float* __restrict__ Pb, float* __restrict__ Pp)
{
  const int d = blockIdx.x * 256 + threadIdx.x;
  const float w = -__expf(tdec[d]);
  const float Lw = (float)CL * w;
  float aa = 0.f, bb = 0.f, pp = -1e38f;
  for (int c = 0; c < NCH; ++c) {
    const size_t idx = (size_t)c * DIM + d;
    Pa[idx] = aa; Pb[idx] = bb; Pp[idx] = pp;
    const float dp = pp + Lw;
    const float sa = Sa[idx], sb = Sb[idx], sp = Sp[idx];
    const float p = fmaxf(dp, sp);
    const float e1 = __expf(dp - p), e2 = __expf(sp - p);
    aa = e1 * aa + e2 * sa;
    bb = e1 * bb + e2 * sb;
    pp = p;
  }
}

// Phase 3: replay chunk from prefix state, emit out*sigmoid_r as bf16.
__global__ void __launch_bounds__(256) wkv_phase3(
    const u16* __restrict__ k, const u16* __restrict__ v, const u16* __restrict__ r,
    const float* __restrict__ Pa, const float* __restrict__ Pb, const float* __restrict__ Pp,
    const float* __restrict__ tfirst, const float* __restrict__ tdec,
    u16* __restrict__ outb)
{
  const int d = blockIdx.y * 256 + threadIdx.x;
  const int c = blockIdx.x;
  const float u = tfirst[d];
  const float w = -__expf(tdec[d]);
  const size_t sidx = (size_t)c * DIM + d;
  float aa = Pa[sidx], bb = Pb[sidx], pp = Pp[sidx];
  const int t0 = c * CL;
  for (int t = t0; t < t0 + CL; ++t) {
    const size_t idx = (size_t)t * DIM + d;
    const float kk = bf2f(k[idx]), vv = bf2f(v[idx]);
    // output uses carry (tokens < t) plus u-bonus for current token
    const float ww = u + kk;
    const float p = fmaxf(pp, ww);
    float e1 = __expf(pp - p), e2 = __expf(ww - p);
    const float out = (e1 * aa + e2 * vv) / (e1 * bb + e2);
    outb[idx] = f2bf(out * bf2f(r[idx]));
    // state update
    const float ww2 = pp + w;
    const float p2 = fmaxf(ww2, kk);
    e1 = __expf(ww2 - p2); e2 = __expf(kk - p2);
    aa = e1 * aa + e2 * vv;
    bb = e1 * bb + e2;
    pp = p2;
  }
}

// ---------------- host-side orchestration ----------------
extern "C" void kernel_launch(void* const* d_in, const int* in_sizes, int n_in,
                              void* d_out, int out_size, void* d_ws, size_t ws_size,
                              hipStream_t stream)
{
  const float* x      = (const float*)d_in[0];
  const float* attk_w = (const float*)d_in[1];
  const float* attk_b = (const float*)d_in[2];
  const float* attv_w = (const float*)d_in[3];
  const float* attv_b = (const float*)d_in[4];
  const float* attr_w = (const float*)d_in[5];
  const float* attr_b = (const float*)d_in[6];
  const float* atto_w = (const float*)d_in[7];
  const float* atto_b = (const float*)d_in[8];
  const float* ffnk_w = (const float*)d_in[9];
  const float* ffnk_b = (const float*)d_in[10];
  const float* ffnv_w = (const float*)d_in[11];
  const float* ffnv_b = (const float*)d_in[12];
  const float* ffnr_w = (const float*)d_in[13];
  const float* ffnr_b = (const float*)d_in[14];
  const float* ln1_g  = (const float*)d_in[15];
  const float* ln1_b  = (const float*)d_in[16];
  const float* ln2_g  = (const float*)d_in[17];
  const float* ln2_b  = (const float*)d_in[18];
  const float* amixk  = (const float*)d_in[19];
  const float* amixv  = (const float*)d_in[20];
  const float* amixr  = (const float*)d_in[21];
  const float* fmixk  = (const float*)d_in[22];
  const float* fmixr  = (const float*)d_in[23];
  const float* tfirst = (const float*)d_in[24];
  const float* tdecay = (const float*)d_in[25];
  float* out = (float*)d_out;

  // workspace carve-up: peak ~254 MiB with aliasing.
  const size_t WE = (size_t)DIM * DIM;   // weight elements
  const size_t SD = (size_t)SEQ * DIM;   // activation elements
  u16* Wbf = (u16*)d_ws;                 // 7 * 8 MiB bf16 weights
  u16* xk  = Wbf + 7 * WE;               // 32 MiB  (later wkvr, later kf2)
  u16* xv  = xk + SD;                    // 32 MiB  (later rz lower half)
  u16* xr  = xv + SD;                    // 32 MiB  (rz upper half)
  u16* kb  = xr + SD;                    // bf16 k  (later xkf)
  u16* vb  = kb + SD;                    // bf16 v  (later xrf)
  u16* rb  = vb + SD;                    // bf16 r  (later rf)
  float* Sa = (float*)(rb + SD);         // 6 x 1 MiB scan states
  float* Sb = Sa + (size_t)NCH * DIM;
  float* Sp = Sb + (size_t)NCH * DIM;
  float* Pa = Sp + (size_t)NCH * DIM;
  float* Pb = Pa + (size_t)NCH * DIM;
  float* Pp = Pb + (size_t)NCH * DIM;
  // aliases (lifetimes disjoint):
  u16*   wkvr = xk;          // wkv*r output, consumed by rz gemm
  float* rz   = (float*)xv;  // f32, spans xv+xr (64 MiB)
  u16*   xkf  = kb;
  u16*   xrf  = vb;
  u16*   rf   = rb;
  u16*   kf2  = xk;

  const dim3 gg(DIM / 128, SEQ / 128);
  const dim3 gwkv(NCH, DIM / 256);

  convert_weights<<<dim3(DIM * DIM / 1024, 7), 256, 0, stream>>>(
      attk_w, attv_w, attr_w, atto_w, ffnk_w, ffnv_w, ffnr_w, Wbf);

  // --- attention branch ---
  ln_mix_kernel<3><<<SEQ, 256, 0, stream>>>(x, ln1_g, ln1_b, amixk, amixv, amixr, xk, xv, xr);
  gemm_bt<0><<<gg, 256, 0, stream>>>(xk, Wbf + 0 * WE, attk_b, nullptr, nullptr, nullptr, kb);
  gemm_bt<0><<<gg, 256, 0, stream>>>(xv, Wbf + 1 * WE, attv_b, nullptr, nullptr, nullptr, vb);
  gemm_bt<1><<<gg, 256, 0, stream>>>(xr, Wbf + 2 * WE, attr_b, nullptr, nullptr, nullptr, rb);
  wkv_phase1<<<gwkv, 256, 0, stream>>>(kb, vb, tdecay, Sa, Sb, Sp);
  wkv_phase2<<<DIM / 256, 256, 0, stream>>>(Sa, Sb, Sp, tdecay, Pa, Pb, Pp);
  wkv_phase3<<<gwkv, 256, 0, stream>>>(kb, vb, rb, Pa, Pb, Pp, tfirst, tdecay, wkvr);
  // rz = x + wkv@atto^T + b   (wkvr in xk; rz into xv+xr region)
  gemm_bt<2><<<gg, 256, 0, stream>>>(wkvr, Wbf + 3 * WE, atto_b, x, nullptr, rz, nullptr);

  // --- channel-mix branch ---
  ln_mix_kernel<2><<<SEQ, 256, 0, stream>>>(rz, ln2_g, ln2_b, fmixk, fmixr, nullptr, xkf, xrf, nullptr);
  gemm_bt<1><<<gg, 256, 0, stream>>>(xrf, Wbf + 6 * WE, ffnr_b, nullptr, nullptr, nullptr, rf);  // rf
  gemm_bt<3><<<gg, 256, 0, stream>>>(xkf, Wbf + 4 * WE, ffnk_b, nullptr, nullptr, nullptr, kf2); // kf^2
  gemm_bt<4><<<gg, 256, 0, stream>>>(kf2, Wbf + 5 * WE, ffnv_b, rz, rf, out, nullptr);           // final
}